// Round 1
// 183.078 us; speedup vs baseline: 1.2055x; 1.2055x over previous
//
#include <hip/hip_runtime.h>
#include <hip/hip_bf16.h>

#define TCH 512
#define MTOT 16384
#define SEQ 2048
#define LN_EPS 1e-5f

typedef __attribute__((ext_vector_type(8))) __bf16 bf16x8;
typedef __attribute__((ext_vector_type(4))) float f32x4;

__device__ __forceinline__ unsigned pkbf(float a, float b) {
  union { __hip_bfloat16 h; unsigned short u; } ca, cb;
  ca.h = __float2bfloat16(a); cb.h = __float2bfloat16(b);
  return (unsigned)ca.u | ((unsigned)cb.u << 16);
}
__device__ __forceinline__ float bf_lo(unsigned u) { return __uint_as_float(u << 16); }
__device__ __forceinline__ float bf_hi(unsigned u) { return __uint_as_float(u & 0xffff0000u); }

__device__ __forceinline__ bf16x8 cvt8(float4 a, float4 b) {
  union { __hip_bfloat16 h; __bf16 v; } u;
  bf16x8 r;
  u.h = __float2bfloat16(a.x); r[0] = u.v;
  u.h = __float2bfloat16(a.y); r[1] = u.v;
  u.h = __float2bfloat16(a.z); r[2] = u.v;
  u.h = __float2bfloat16(a.w); r[3] = u.v;
  u.h = __float2bfloat16(b.x); r[4] = u.v;
  u.h = __float2bfloat16(b.y); r[5] = u.v;
  u.h = __float2bfloat16(b.z); r[6] = u.v;
  u.h = __float2bfloat16(b.w); r[7] = u.v;
  return r;
}

// log2(e)/sqrt(3): folded into wq/bq so attention uses exp2 directly
#define QSCALE 0.8329517853860118f

// ---------------- prep ------------------------------------------------------
__global__ __launch_bounds__(256) void prep_kernel(
    const float* __restrict__ w2,
    const float* __restrict__ wo, const float* __restrict__ bo,
    const float* __restrict__ wq, const float* __restrict__ bq,
    const float* __restrict__ wk, const float* __restrict__ bk,
    const float* __restrict__ wv, const float* __restrict__ bv,
    __hip_bfloat16* __restrict__ w2b,
    float4* __restrict__ wo_eff4,
    __hip_bfloat16* __restrict__ wqkvb, float* __restrict__ qkvbias)
{
  int i = blockIdx.x * 256 + threadIdx.x;   // grid covers 512*512 exactly
  w2b[i] = __float2bfloat16(w2[i]);
  if (i < TCH) {
    float s0 = 0.f, s1 = 0.f, s2 = 0.f;
    #pragma unroll
    for (int h = 0; h < 6; ++h) {
      s0 += wo[i*18 + h*3 + 0];
      s1 += wo[i*18 + h*3 + 1];
      s2 += wo[i*18 + h*3 + 2];
    }
    wo_eff4[i] = make_float4(s0, s1, s2, bo[i]);
  }
  if (i < 16 * TCH) {
    int row = i >> 9, k = i & 511;
    float v;
    if      (row < 3) v = wq[row * TCH + k] * QSCALE;
    else if (row < 6) v = wk[(row - 3) * TCH + k];
    else if (row < 9) v = wv[(row - 6) * TCH + k];
    else              v = 0.f;
    wqkvb[i] = __float2bfloat16(v);
  }
  if (i < 16) {
    float v;
    if      (i < 3) v = bq[i] * QSCALE;
    else if (i < 6) v = bk[i - 3];
    else if (i < 9) v = bv[i - 6];
    else            v = 0.f;
    qkvbias[i] = v;
  }
}

// ---------------- prep2: fold w1 through wo_eff -----------------------------
// weff4[i] = sum_k w1[i,k] * wo_eff4[k]  (+ b1[i] into .w, since .w carries bo)
__global__ __launch_bounds__(256) void prep2_kernel(
    const float* __restrict__ w1, const float* __restrict__ b1,
    const float4* __restrict__ wo_eff4, float4* __restrict__ weff4)
{
  const int t = threadIdx.x, w = t >> 6, l = t & 63;
  const int i = blockIdx.x * 4 + w;         // 128 blocks * 4 waves = 512 rows
  float sx = 0.f, sy = 0.f, sz = 0.f, sw = 0.f;
  #pragma unroll
  for (int j = 0; j < 8; ++j) {
    const int k = j * 64 + l;
    const float a = w1[(size_t)i * TCH + k];
    const float4 e = wo_eff4[k];
    sx += a * e.x; sy += a * e.y; sz += a * e.z; sw += a * e.w;
  }
  #pragma unroll
  for (int off = 1; off < 64; off <<= 1) {
    sx += __shfl_xor(sx, off, 64);
    sy += __shfl_xor(sy, off, 64);
    sz += __shfl_xor(sz, off, 64);
    sw += __shfl_xor(sw, off, 64);
  }
  if (l == 0) weff4[i] = make_float4(sx, sy, sz, sw + b1[i]);
}

// ---------------- qkv via MFMA ---------------------------------------------
__global__ __launch_bounds__(256) void qkv_kernel(
    const float* __restrict__ x,
    const __hip_bfloat16* __restrict__ wqkvb, const float* __restrict__ qkvbias,
    float4* __restrict__ q4, uint4* __restrict__ kvp)
{
  const int t = threadIdx.x, wv = t >> 6, ln = t & 63;
  const int l16 = ln & 15, quad = ln >> 4;
  const int row0 = blockIdx.x * 64 + wv * 16;

  bf16x8 bfr[16];
  #pragma unroll
  for (int ks = 0; ks < 16; ++ks)
    bfr[ks] = *reinterpret_cast<const bf16x8*>(wqkvb + l16 * TCH + ks * 32 + quad * 8);

  const float* xp = x + (size_t)(row0 + l16) * TCH + quad * 8;

  float4 xa0 = *(const float4*)xp,        xb0 = *(const float4*)(xp + 4);
  float4 xa1 = *(const float4*)(xp + 32), xb1 = *(const float4*)(xp + 36);
  f32x4 acc = {};
  #pragma unroll
  for (int ks = 0; ks < 16; ++ks) {
    float4 xa2 = {}, xb2 = {};
    if (ks < 14) {
      xa2 = *(const float4*)(xp + (ks + 2) * 32);
      xb2 = *(const float4*)(xp + (ks + 2) * 32 + 4);
    }
    bf16x8 af = cvt8(xa0, xb0);
    acc = __builtin_amdgcn_mfma_f32_16x16x32_bf16(af, bfr[ks], acc, 0, 0, 0);
    xa0 = xa1; xb0 = xb1; xa1 = xa2; xb1 = xb2;
  }

  __shared__ float tr[4][16][17];
  #pragma unroll
  for (int r = 0; r < 4; ++r) tr[wv][quad * 4 + r][l16] = acc[r];
  __syncthreads();

  if (ln < 32) {
    const int row  = ln & 15;
    const int grow = row0 + row;
    float c[9];
    #pragma unroll
    for (int j = 0; j < 9; ++j) c[j] = tr[wv][row][j] + qkvbias[j];
    if (ln < 16) {
      q4[grow] = make_float4(c[0], c[1], c[2], 0.f);   // pre-scaled
    } else {
      kvp[grow] = make_uint4(pkbf(c[3], c[4]), pkbf(c[5], c[6]), pkbf(c[7], c[8]), 0u);
    }
  }
}

// ---------------- attention + rank-3 r0 + LN1 (fused) ----------------------
// r0 = x + z @ weff^T + beff ; r1 = LN(r0). Each block owns 64 full rows.
__global__ __launch_bounds__(1024) void attn_kernel(
    const float4* __restrict__ q4, const uint4* __restrict__ kvp,
    const float* __restrict__ x, const float4* __restrict__ weff4,
    const float* __restrict__ gamma, const float* __restrict__ beta,
    __hip_bfloat16* __restrict__ r0b, __hip_bfloat16* __restrict__ r1b)
{
  __shared__ float4 part[16 * 64];  // 16 KB
  __shared__ float4 zbuf[64];       // 1 KB

  const int b    = blockIdx.x >> 5;
  const int qc   = blockIdx.x & 31;
  const int base = b * SEQ;
  const int tid  = threadIdx.x;
  const int wave = tid >> 6;
  const int lane = tid & 63;
  const float4 q = q4[base + qc * 64 + lane];   // pre-scaled by log2e/sqrt(3)

  const int wu = __builtin_amdgcn_readfirstlane(wave);
  const uint4* kvw = kvp + base + wu * 128;     // wave-uniform -> s_load

  float l[4] = {}, a0[4] = {}, a1[4] = {}, a2[4] = {};
  #pragma unroll 4
  for (int i = 0; i < 32; ++i) {
    #pragma unroll
    for (int s = 0; s < 4; ++s) {               // 4 independent chains
      uint4 rec = kvw[s * 32 + i];
      float sc = bf_lo(rec.x) * q.x + bf_hi(rec.x) * q.y + bf_lo(rec.y) * q.z;
      float p = __builtin_amdgcn_exp2f(sc);
      l[s]  += p;
      a0[s] += p * bf_hi(rec.y);
      a1[s] += p * bf_lo(rec.z);
      a2[s] += p * bf_hi(rec.z);
    }
  }
  part[wave * 64 + lane] = make_float4(l[0]+l[1]+l[2]+l[3],
                                       a0[0]+a0[1]+a0[2]+a0[3],
                                       a1[0]+a1[1]+a1[2]+a1[3],
                                       a2[0]+a2[1]+a2[2]+a2[3]);
  __syncthreads();

  if (tid < 64) {
    float L = 0.f, A0 = 0.f, A1 = 0.f, A2 = 0.f;
    #pragma unroll
    for (int w = 0; w < 16; ++w) {
      float4 p = part[w * 64 + tid];
      L += p.x; A0 += p.y; A1 += p.z; A2 += p.w;
    }
    const float inv = 1.f / L;
    zbuf[tid] = make_float4(A0 * inv, A1 * inv, A2 * inv, 0.f);
  }
  __syncthreads();

  // ---- epilogue: each wave handles 4 full rows (16 waves * 4 = 64 rows) ----
  const int c0 = lane * 8;
  float4 wv[8];
  #pragma unroll
  for (int j = 0; j < 8; ++j) wv[j] = weff4[c0 + j];   // (weff0..2, beff)
  const float4 g0  = *(const float4*)(gamma + c0);
  const float4 g1  = *(const float4*)(gamma + c0 + 4);
  const float4 be0 = *(const float4*)(beta  + c0);
  const float4 be1 = *(const float4*)(beta  + c0 + 4);
  const float gg[8] = {g0.x,g0.y,g0.z,g0.w,g1.x,g1.y,g1.z,g1.w};
  const float bb[8] = {be0.x,be0.y,be0.z,be0.w,be1.x,be1.y,be1.z,be1.w};

  #pragma unroll
  for (int qi = 0; qi < 4; ++qi) {
    const int qloc = wave * 4 + qi;
    const int grow = base + qc * 64 + qloc;
    const float4 z = zbuf[qloc];
    const float* xr = x + (size_t)grow * TCH + c0;
    const float4 x0 = *(const float4*)xr;
    const float4 x1 = *(const float4*)(xr + 4);
    const float xv[8] = {x0.x,x0.y,x0.z,x0.w,x1.x,x1.y,x1.z,x1.w};
    float r0v[8], s = 0.f, sq = 0.f;
    #pragma unroll
    for (int j = 0; j < 8; ++j) {
      float v = xv[j] + z.x * wv[j].x + z.y * wv[j].y + z.z * wv[j].z + wv[j].w;
      r0v[j] = v; s += v; sq += v * v;
    }
    #pragma unroll
    for (int off = 1; off < 64; off <<= 1) {
      s  += __shfl_xor(s,  off, 64);
      sq += __shfl_xor(sq, off, 64);
    }
    const float mu = s * (1.f / TCH);
    const float rs = rsqrtf(sq * (1.f / TCH) - mu * mu + LN_EPS);
    *(bf16x8*)(r0b + (size_t)grow * TCH + c0) =
        cvt8(make_float4(r0v[0], r0v[1], r0v[2], r0v[3]),
             make_float4(r0v[4], r0v[5], r0v[6], r0v[7]));
    float r1v[8];
    #pragma unroll
    for (int j = 0; j < 8; ++j) r1v[j] = (r0v[j] - mu) * rs * gg[j] + bb[j];
    *(bf16x8*)(r1b + (size_t)grow * TCH + c0) =
        cvt8(make_float4(r1v[0], r1v[1], r1v[2], r1v[3]),
             make_float4(r1v[4], r1v[5], r1v[6], r1v[7]));
  }
}

// ---------------- GEMM2 (full rows) + residual + LN2 fused ------------------
// out = LN(r0 + r1 @ w2^T + b2). 256 blocks x 512 thr (8 waves);
// block owns 64 rows x all 512 cols so LN2 completes in-block.
__global__ __launch_bounds__(512) void gemm2_kernel(
    const __hip_bfloat16* __restrict__ A,    // r1b [16384,512]
    const __hip_bfloat16* __restrict__ W,    // w2b [512,512], row = out col
    const float* __restrict__ bias,          // b2
    const __hip_bfloat16* __restrict__ res,  // r0b
    const float* __restrict__ gamma, const float* __restrict__ beta,
    float* __restrict__ out)
{
  __shared__ __align__(16) __hip_bfloat16 At[2][4][64][8];    // 8 KB
  __shared__ __align__(16) __hip_bfloat16 Wt[2][4][512][8];   // 64 KB
  __shared__ float redS[64][4], redQ[64][4];                  // 2 KB
  __shared__ float muL[64], rsL[64];

  const int row0 = blockIdx.x * 64;
  const int t    = threadIdx.x;
  const int w    = t >> 6;                  // 0..7
  const int l    = t & 63;
  const int l16  = l & 15, quad = l >> 4;
  const int wr   = w >> 2, wc = w & 3;      // wave tile: 32 rows x 128 cols

  auto stage = [&](int ks, int buf) {
    if (t < 256) {                           // A-tile: 64 rows x 32 k
      const int srow = t & 63, qa = t >> 6;
      __builtin_amdgcn_global_load_lds(
          (const __attribute__((address_space(1))) void*)(A + (size_t)(row0 + srow) * TCH + ks * 32 + qa * 8),
          (__attribute__((address_space(3))) void*)&At[buf][qa][srow][0], 16, 0, 0);
    }
    #pragma unroll
    for (int j = 0; j < 4; ++j) {            // W-tile: 512 rows x 32 k
      __builtin_amdgcn_global_load_lds(
          (const __attribute__((address_space(1))) void*)(W + (size_t)t * TCH + ks * 32 + j * 8),
          (__attribute__((address_space(3))) void*)&Wt[buf][j][t][0], 16, 0, 0);
    }
  };

  f32x4 acc[2][8] = {};
  stage(0, 0);
  for (int ks = 0; ks < 16; ++ks) {
    const int cur = ks & 1;
    __syncthreads();
    if (ks < 15) stage(ks + 1, cur ^ 1);
    bf16x8 af[2], bfv[8];
    #pragma unroll
    for (int m = 0; m < 2; ++m)
      af[m] = *reinterpret_cast<const bf16x8*>(&At[cur][quad][wr * 32 + m * 16 + l16][0]);
    #pragma unroll
    for (int n = 0; n < 8; ++n)
      bfv[n] = *reinterpret_cast<const bf16x8*>(&Wt[cur][quad][wc * 128 + n * 16 + l16][0]);
    #pragma unroll
    for (int m = 0; m < 2; ++m)
      #pragma unroll
      for (int n = 0; n < 8; ++n)
        acc[m][n] = __builtin_amdgcn_mfma_f32_16x16x32_bf16(af[m], bfv[n], acc[m][n], 0, 0, 0);
  }

  // epilogue: v = acc + b2 + r0 ; row stats ; then LN2 -> out (fp32)
  #pragma unroll
  for (int m = 0; m < 2; ++m) {
    #pragma unroll
    for (int r = 0; r < 4; ++r) {
      const int lrow = wr * 32 + m * 16 + quad * 4 + r;
      const int grow = row0 + lrow;
      float s = 0.f, sq = 0.f;
      #pragma unroll
      for (int n = 0; n < 8; ++n) {
        const int col = wc * 128 + n * 16 + l16;
        float v = acc[m][n][r] + bias[col] +
                  __bfloat162float(res[(size_t)grow * TCH + col]);
        acc[m][n][r] = v; s += v; sq += v * v;
      }
      #pragma unroll
      for (int off = 1; off < 16; off <<= 1) {   // reduce across l16 group
        s  += __shfl_xor(s,  off, 64);
        sq += __shfl_xor(sq, off, 64);
      }
      if (l16 == 0) { redS[lrow][wc] = s; redQ[lrow][wc] = sq; }
    }
  }
  __syncthreads();
  if (t < 64) {
    const float S = redS[t][0] + redS[t][1] + redS[t][2] + redS[t][3];
    const float Q = redQ[t][0] + redQ[t][1] + redQ[t][2] + redQ[t][3];
    const float mu = S * (1.f / TCH);
    muL[t] = mu;
    rsL[t] = rsqrtf(Q * (1.f / TCH) - mu * mu + LN_EPS);
  }
  __syncthreads();
  #pragma unroll
  for (int m = 0; m < 2; ++m) {
    #pragma unroll
    for (int r = 0; r < 4; ++r) {
      const int lrow = wr * 32 + m * 16 + quad * 4 + r;
      const int grow = row0 + lrow;
      const float mu = muL[lrow], rs = rsL[lrow];
      #pragma unroll
      for (int n = 0; n < 8; ++n) {
        const int col = wc * 128 + n * 16 + l16;
        out[(size_t)grow * TCH + col] =
            (acc[m][n][r] - mu) * rs * gamma[col] + beta[col];
      }
    }
  }
}

// ---------------- host ------------------------------------------------------
extern "C" void kernel_launch(void* const* d_in, const int* in_sizes, int n_in,
                              void* d_out, int out_size, void* d_ws, size_t ws_size,
                              hipStream_t stream) {
  (void)in_sizes; (void)n_in; (void)out_size; (void)ws_size;
  const float* x     = (const float*)d_in[0];
  const float* wq    = (const float*)d_in[1];
  const float* bq    = (const float*)d_in[2];
  const float* wk    = (const float*)d_in[3];
  const float* bk    = (const float*)d_in[4];
  const float* wv    = (const float*)d_in[5];
  const float* bv    = (const float*)d_in[6];
  const float* wo    = (const float*)d_in[7];
  const float* bo    = (const float*)d_in[8];
  const float* w1    = (const float*)d_in[9];
  const float* b1    = (const float*)d_in[10];
  const float* w2    = (const float*)d_in[11];
  const float* b2    = (const float*)d_in[12];
  const float* gamma = (const float*)d_in[13];
  const float* beta  = (const float*)d_in[14];
  float* out = (float*)d_out;

  char* ws = (char*)d_ws;
  size_t off = 0;
  float4* q4      = (float4*)(ws + off); off += (size_t)MTOT * 16;
  uint4*  kvp     = (uint4*)(ws + off);  off += (size_t)MTOT * 16;
  float4* wo_eff4 = (float4*)(ws + off); off += (size_t)TCH * 16;
  float4* weff4   = (float4*)(ws + off); off += (size_t)TCH * 16;
  __hip_bfloat16* w2b   = (__hip_bfloat16*)(ws + off); off += (size_t)TCH * TCH * 2;
  __hip_bfloat16* wqkvb = (__hip_bfloat16*)(ws + off); off += (size_t)16 * TCH * 2;
  float*          qkvbias = (float*)(ws + off);        off += 64;
  __hip_bfloat16* r0b = (__hip_bfloat16*)(ws + off); off += (size_t)MTOT * TCH * 2;  // 16 MB
  __hip_bfloat16* r1b = (__hip_bfloat16*)(ws + off); off += (size_t)MTOT * TCH * 2;  // 16 MB

  prep_kernel<<<(TCH*TCH)/256, 256, 0, stream>>>(
      w2, wo, bo, wq, bq, wk, bk, wv, bv, w2b, wo_eff4, wqkvb, qkvbias);
  prep2_kernel<<<TCH/4, 256, 0, stream>>>(w1, b1, wo_eff4, weff4);
  qkv_kernel<<<MTOT/64, 256, 0, stream>>>(x, wqkvb, qkvbias, q4, kvp);
  // r0 = x + z @ weff^T + beff ; r1 = LN(r0)   (attention fused)
  attn_kernel<<<MTOT/64, 1024, 0, stream>>>(q4, kvp, x, weff4, gamma, beta, r0b, r1b);
  // out = LN(r0 + r1 @ w2^T + b2)              (GEMM + LN2 fused)
  gemm2_kernel<<<MTOT/64, 512, 0, stream>>>(r1b, w2b, b2, r0b, gamma, beta, out);
}